// Round 9
// baseline (109.254 us; speedup 1.0000x reference)
//
#include <hip/hip_runtime.h>
#include <hip/hip_bf16.h>
#include <stdint.h>

#define B_DIM 16384
#define H_DIM 512
#define KTOT  1024   // I + H
#define NP    2048   // 4 gates * H

typedef __attribute__((ext_vector_type(8))) short short8;
typedef __attribute__((ext_vector_type(4))) float floatx4;
typedef __attribute__((ext_vector_type(16))) float floatx16;

static __device__ __forceinline__ unsigned short f2bf(float f) {
  unsigned int u = __float_as_uint(f);
  u += 0x7fffu + ((u >> 16) & 1u);
  return (unsigned short)(u >> 16);
}

static __device__ __forceinline__ short8 cvt8(floatx4 v0, floatx4 v1) {
  short8 o;
#pragma unroll
  for (int i = 0; i < 4; ++i) {
    o[i]     = (short)f2bf(v0[i]);
    o[i + 4] = (short)f2bf(v1[i]);
  }
  return o;
}

// ---------------------------------------------------------------------------
// Packed A (bf16), 32x32x16 frag-linear (R5-validated mapping), BK=32 tiles:
//   unit u: lane=u&63, kk=(u>>6)&1, m=(u>>7)&1, wr=(u>>8)&1, kt=(u>>9)&31,
//           bm=u>>14
//   row = bm*128 + wr*64 + m*32 + (lane&31)
//   k   = kt*32 + kk*16 + (lane>>5)*8 + j     (k<512 -> x, else z)
// Tile (bm,kt) = 4096 ushorts = 8KB = exact LDS A-tile image.
// ---------------------------------------------------------------------------
__global__ __launch_bounds__(256) void pack_a_kernel(
    const float* __restrict__ x, const float* __restrict__ z,
    unsigned short* __restrict__ Ap) {
  int u    = blockIdx.x * 256 + threadIdx.x;
  int lane = u & 63;
  int kk   = (u >> 6) & 1;
  int m    = (u >> 7) & 1;
  int wr   = (u >> 8) & 1;
  int kt   = (u >> 9) & 31;
  int bm   = u >> 14;
  int row  = bm * 128 + wr * 64 + m * 32 + (lane & 31);
  int k    = kt * 32 + kk * 16 + ((lane >> 5) << 3);
  const float* src = (k < 512) ? (x + (uint64_t)row * 512 + k)
                               : (z + (uint64_t)row * 512 + (k - 512));
  floatx4 v0 = *reinterpret_cast<const floatx4*>(src);
  floatx4 v1 = *reinterpret_cast<const floatx4*>(src + 4);
  *reinterpret_cast<short8*>(Ap + (uint64_t)u * 8) = cvt8(v0, v1);
}

// ---------------------------------------------------------------------------
// Packed B (bf16), 32x32x16 gate-major frags, BK=32 tiles:
//   unit u: lane=u&63, kk=(u>>6)&1, g=(u>>7)&3, wc=(u>>9)&1, kt=(u>>10)&31,
//           bn=u>>15
//   h = bn*64 + wc*32 + (lane&31); gate g
//   k = kt*32 + kk*16 + (lane>>5)*8 + j       (k<512 -> W_g, else U_g)
// Tile (bn,kt) = 8192 ushorts = 16KB = exact LDS B-tile image.
// ---------------------------------------------------------------------------
__global__ __launch_bounds__(256) void pack_w_kernel(
    const float* __restrict__ Wi, const float* __restrict__ Wf,
    const float* __restrict__ Wc, const float* __restrict__ Wo,
    const float* __restrict__ Ui, const float* __restrict__ Uf,
    const float* __restrict__ Uc, const float* __restrict__ Uo,
    unsigned short* __restrict__ Bp) {
  int u    = blockIdx.x * 256 + threadIdx.x;
  int lane = u & 63;
  int kk   = (u >> 6) & 1;
  int g    = (u >> 7) & 3;
  int wc   = (u >> 9) & 1;
  int kt   = (u >> 10) & 31;
  int bn   = u >> 15;
  int h    = bn * 64 + wc * 32 + (lane & 31);
  int k    = kt * 32 + kk * 16 + ((lane >> 5) << 3);
  const float* src;
  if (k < 512) {
    const float* W = (g == 0) ? Wi : (g == 1) ? Wf : (g == 2) ? Wc : Wo;
    src = W + (uint64_t)h * 512 + k;
  } else {
    const float* U = (g == 0) ? Ui : (g == 1) ? Uf : (g == 2) ? Uc : Uo;
    src = U + (uint64_t)h * 512 + (k - 512);
  }
  floatx4 v0 = *reinterpret_cast<const floatx4*>(src);
  floatx4 v1 = *reinterpret_cast<const floatx4*>(src + 4);
  *reinterpret_cast<short8*>(Bp + (uint64_t)u * 8) = cvt8(v0, v1);
}

// stage A-tile (8KB): 256 thr x 16B x 2 instrs; B-tile (16KB): x 4
static __device__ __forceinline__ void stageA(const unsigned short* g,
                                              unsigned short* l, int tid) {
#pragma unroll
  for (int r = 0; r < 2; ++r)
    __builtin_amdgcn_global_load_lds(
        (const __attribute__((address_space(1))) void*)(g + r * 2048 + tid * 8),
        (__attribute__((address_space(3))) void*)(l + r * 2048 + tid * 8), 16, 0, 0);
}
static __device__ __forceinline__ void stageB(const unsigned short* g,
                                              unsigned short* l, int tid) {
#pragma unroll
  for (int r = 0; r < 4; ++r)
    __builtin_amdgcn_global_load_lds(
        (const __attribute__((address_space(1))) void*)(g + r * 2048 + tid * 8),
        (__attribute__((address_space(3))) void*)(l + r * 2048 + tid * 8), 16, 0, 0);
}

#define WAITBAR(S)                                  \
  asm volatile(S ::: "memory");                     \
  __builtin_amdgcn_sched_barrier(0);                \
  __builtin_amdgcn_s_barrier();                     \
  __builtin_amdgcn_sched_barrier(0);

// one K-tile body: 12 ds_read_b128, 16 MFMA(32x32x16), 6 global_load_lds
// (2 tiles ahead). Relaxed interior (R6/R8 winner structure).
#define KTILE_BODY(DO_STAGE)                                                \
  {                                                                         \
    short8 aF[2][2], bF[4][2];                                              \
    _Pragma("unroll")                                                       \
    for (int g = 0; g < 4; ++g) {                                           \
      bF[g][0] = *reinterpret_cast<const short8*>(bC + g * 1024);           \
      bF[g][1] = *reinterpret_cast<const short8*>(bC + g * 1024 + 512);     \
    }                                                                       \
    _Pragma("unroll")                                                       \
    for (int m = 0; m < 2; ++m) {                                           \
      aF[m][0] = *reinterpret_cast<const short8*>(aC + m * 1024);           \
      aF[m][1] = *reinterpret_cast<const short8*>(aC + m * 1024 + 512);     \
    }                                                                       \
    if (DO_STAGE) { stageA(gAs, aN, tid); stageB(gBs, bN, tid); }           \
    __builtin_amdgcn_s_setprio(1);                                          \
    _Pragma("unroll")                                                       \
    for (int kk = 0; kk < 2; ++kk)                                          \
      _Pragma("unroll")                                                     \
      for (int m = 0; m < 2; ++m)                                           \
        _Pragma("unroll")                                                   \
        for (int g = 0; g < 4; ++g)                                         \
          acc[m][g] = __builtin_amdgcn_mfma_f32_32x32x16_bf16(              \
              aF[m][kk], bF[g][kk], acc[m][g], 0, 0, 0);                    \
    __builtin_amdgcn_s_setprio(0);                                          \
  }

// ---------------------------------------------------------------------------
// GEMM M=16384 Np=2048 K=1024. Tile 128x256np, BK=32, 4 waves (2wr x 2wc),
// wave = 64 rows x 128 np (4 gates x 32 h) via 2x4 32x32x16 frags;
// acc[2][4] floatx16 = 128 regs (R5's spill bug fixed by halving m-frags).
// 32x32 ceiling 2495 TF (vs 2075 for 16x16) and HALF the MFMA instr count
// at identical LDS traffic -> less issue/latency pressure.
// Structure = R8 winner: ring-3 LDS 72KB (2 blocks/CU), depth-2 prefetch,
// one barrier/tile, steady-state counted vmcnt(6).
// ---------------------------------------------------------------------------
__global__ __launch_bounds__(256, 2) void lstm_gemm_kernel(
    const unsigned short* __restrict__ Ap,
    const unsigned short* __restrict__ Bp,
    const float* __restrict__ z,
    const float* __restrict__ b_i, const float* __restrict__ b_f,
    const float* __restrict__ b_c, const float* __restrict__ b_o,
    float* __restrict__ out) {
  __shared__ unsigned short lds[36864];  // 72KB = 3 bufs x (A 8KB | B 16KB)

  int tid  = threadIdx.x;
  int bid  = blockIdx.x;
  int sw   = (bid & 7) * 128 + (bid >> 3);  // 1024 % 8 == 0 -> bijective
  int bn   = sw & 7;     // 8 N-tiles (64 h * 4 gates = 256 np)
  int bm   = sw >> 3;    // 128 M-tiles (128 rows)
  int lane = tid & 63;
  int wid  = tid >> 6;   // 0..3
  int wr   = wid >> 1;   // 0..1 -> 64 rows
  int wc   = wid & 1;    // 0..1 -> 32 h * 4 gates

  floatx16 acc[2][4];
#pragma unroll
  for (int m = 0; m < 2; ++m)
#pragma unroll
    for (int g = 0; g < 4; ++g)
#pragma unroll
      for (int r = 0; r < 16; ++r)
        acc[m][g][r] = 0.f;

  const unsigned short* gA = Ap + (uint64_t)bm * (32 * 4096);
  const unsigned short* gB = Bp + (uint64_t)bn * (32 * 8192);

  // prologue: stage tiles 0 (buf0) and 1 (buf1); wait tile0 -> vmcnt(6)
  stageA(gA, lds, tid);
  stageB(gB, lds + 4096, tid);
  stageA(gA + 4096, lds + 12288, tid);
  stageB(gB + 8192, lds + 12288 + 4096, tid);
  asm volatile("s_waitcnt vmcnt(6)" ::: "memory");
  __builtin_amdgcn_sched_barrier(0);
  __builtin_amdgcn_s_barrier();
  __builtin_amdgcn_sched_barrier(0);

  int cur = 0;
#pragma unroll 1
  for (int kt = 0; kt < 30; ++kt) {
    int nxt2 = (cur >= 1) ? cur - 1 : 2;  // (cur+2)%3
    const unsigned short* aC = lds + cur * 12288 + wr * 2048 + lane * 8;
    const unsigned short* bC = lds + cur * 12288 + 4096 + wc * 4096 + lane * 8;
    unsigned short* aN = lds + nxt2 * 12288;
    unsigned short* bN = aN + 4096;
    const unsigned short* gAs = gA + (kt + 2) * 4096;
    const unsigned short* gBs = gB + (kt + 2) * 8192;

    KTILE_BODY(true)
    WAITBAR("s_waitcnt vmcnt(6)")   // kt+1 landed; kt+2's 6 stay in flight
    cur = (cur == 2) ? 0 : cur + 1;
  }

  // tile 30: no staging; tile 31 must be fully landed
  {
    const unsigned short* aC = lds + cur * 12288 + wr * 2048 + lane * 8;
    const unsigned short* bC = lds + cur * 12288 + 4096 + wc * 4096 + lane * 8;
    unsigned short* aN = nullptr; unsigned short* bN = nullptr;
    const unsigned short* gAs = nullptr; const unsigned short* gBs = nullptr;
    KTILE_BODY(false)
    WAITBAR("s_waitcnt vmcnt(0)")
    cur = (cur == 2) ? 0 : cur + 1;
  }
  // tile 31: last, no barrier
  {
    const unsigned short* aC = lds + cur * 12288 + wr * 2048 + lane * 8;
    const unsigned short* bC = lds + cur * 12288 + 4096 + wc * 4096 + lane * 8;
    unsigned short* aN = nullptr; unsigned short* bN = nullptr;
    const unsigned short* gAs = nullptr; const unsigned short* gBs = nullptr;
    KTILE_BODY(false)
  }

  // ---- fused LSTM epilogue (lane-local: acc frag index g == gate)
  // 32x32 C/D map (verified m74/m101 + R5 end-to-end):
  //   col = lane&31, row = (r&3) + 8*(r>>2) + 4*(lane>>5)
  int h = bn * 64 + wc * 32 + (lane & 31);
  float vbi = b_i[h], vbf = b_f[h], vbc = b_c[h], vbo = b_o[h];
  int rb = bm * 128 + wr * 64 + ((lane >> 5) << 2);
  float* outH = out;
  float* outC = out + (uint64_t)B_DIM * H_DIM;
#pragma unroll
  for (int m = 0; m < 2; ++m) {
#pragma unroll
    for (int r = 0; r < 16; ++r) {
      int row = rb + m * 32 + (r & 3) + ((r >> 2) << 3);
      float pi = acc[m][0][r] + vbi;
      float pf = acc[m][1][r] + vbf;
      float pc = acc[m][2][r] + vbc;
      float po = acc[m][3][r] + vbo;
      float gi = 1.f / (1.f + __expf(-pi));
      float gf = 1.f / (1.f + __expf(-pf));
      float gc = 1.f - 2.f / (__expf(2.f * pc) + 1.f);  // tanh
      float go = 1.f / (1.f + __expf(-po));
      float zv = z[(uint64_t)row * H_DIM + h];
      float cn = gf * zv + gi * gc;
      float hn = go * (1.f - 2.f / (__expf(2.f * cn) + 1.f));
      outH[(uint64_t)row * H_DIM + h] = hn;
      outC[(uint64_t)row * H_DIM + h] = cn;
    }
  }
}

extern "C" void kernel_launch(void* const* d_in, const int* in_sizes, int n_in,
                              void* d_out, int out_size, void* d_ws, size_t ws_size,
                              hipStream_t stream) {
  const float* z  = (const float*)d_in[0];
  const float* x  = (const float*)d_in[1];
  const float* Wi = (const float*)d_in[2];
  const float* Wf = (const float*)d_in[3];
  const float* Wc = (const float*)d_in[4];
  const float* Wo = (const float*)d_in[5];
  const float* bi = (const float*)d_in[6];
  const float* bf = (const float*)d_in[7];
  const float* bc = (const float*)d_in[8];
  const float* bo = (const float*)d_in[9];
  const float* Ui = (const float*)d_in[10];
  const float* Uf = (const float*)d_in[11];
  const float* Uc = (const float*)d_in[12];
  const float* Uo = (const float*)d_in[13];

  unsigned short* Ap = (unsigned short*)d_ws;                          // 32 MB
  unsigned short* Bp = (unsigned short*)((char*)d_ws
                        + (size_t)B_DIM * KTOT * sizeof(unsigned short)); // +4 MB
  float* out = (float*)d_out;

  hipLaunchKernelGGL(pack_w_kernel, dim3((size_t)NP * KTOT / 8 / 256), dim3(256), 0, stream,
                     Wi, Wf, Wc, Wo, Ui, Uf, Uc, Uo, Bp);
  hipLaunchKernelGGL(pack_a_kernel, dim3((size_t)B_DIM * KTOT / 8 / 256), dim3(256), 0, stream,
                     x, z, Ap);
  hipLaunchKernelGGL(lstm_gemm_kernel, dim3(1024), dim3(256), 0, stream,
                     Ap, Bp, z, bi, bf, bc, bo, out);
}

// Round 10
// 100.322 us; speedup vs baseline: 1.0890x; 1.0890x over previous
//
#include <hip/hip_runtime.h>
#include <hip/hip_bf16.h>
#include <stdint.h>

#define B_DIM 16384
#define H_DIM 512
#define KTOT  1024   // I + H
#define NP    2048   // 4 gates * H

typedef __attribute__((ext_vector_type(8))) short short8;
typedef __attribute__((ext_vector_type(4))) float floatx4;

static __device__ __forceinline__ unsigned short f2bf(float f) {
  unsigned int u = __float_as_uint(f);
  u += 0x7fffu + ((u >> 16) & 1u);
  return (unsigned short)(u >> 16);
}

static __device__ __forceinline__ short8 cvt8(floatx4 v0, floatx4 v1) {
  short8 o;
#pragma unroll
  for (int i = 0; i < 4; ++i) {
    o[i]     = (short)f2bf(v0[i]);
    o[i + 4] = (short)f2bf(v1[i]);
  }
  return o;
}

// ---------------------------------------------------------------------------
// Packed A (bf16), 16x16x32 frag-linear, BK=32 tiles (unchanged from R8):
//   u = bm*32768 + kt*1024 + wr*512 + mh*256 + m4*64 + lane   (units of 8)
//   row = bm*256 + wr*128 + mh*64 + m4*16 + (lane&15)
//   k   = kt*32 + (lane>>4)*8 + j          (k<512 -> x, else z)
// ---------------------------------------------------------------------------
__global__ __launch_bounds__(256) void pack_a_kernel(
    const float* __restrict__ x, const float* __restrict__ z,
    unsigned short* __restrict__ Ap) {
  int u    = blockIdx.x * 256 + threadIdx.x;
  int lane = u & 63;
  int m4   = (u >> 6) & 3;
  int mh   = (u >> 8) & 1;
  int wr   = (u >> 9) & 1;
  int kt   = (u >> 10) & 31;
  int bm   = u >> 15;
  int row  = bm * 256 + wr * 128 + mh * 64 + m4 * 16 + (lane & 15);
  int k    = kt * 32 + ((lane >> 4) << 3);
  const float* src = (k < 512) ? (x + (uint64_t)row * 512 + k)
                               : (z + (uint64_t)row * 512 + (k - 512));
  floatx4 v0 = *reinterpret_cast<const floatx4*>(src);
  floatx4 v1 = *reinterpret_cast<const floatx4*>(src + 4);
  *reinterpret_cast<short8*>(Ap + (uint64_t)u * 8) = cvt8(v0, v1);
}

// ---------------------------------------------------------------------------
// Packed B (bf16), gate-major frags, BK=32 tiles (unchanged from R8):
//   u = bn*16384 + kt*512 + wc*256 + g*64 + lane   (units of 8)
//   h = bn*32 + wc*16 + (lane&15); gate g; k = kt*32 + (lane>>4)*8 + j
// ---------------------------------------------------------------------------
__global__ __launch_bounds__(256) void pack_w_kernel(
    const float* __restrict__ Wi, const float* __restrict__ Wf,
    const float* __restrict__ Wc, const float* __restrict__ Wo,
    const float* __restrict__ Ui, const float* __restrict__ Uf,
    const float* __restrict__ Uc, const float* __restrict__ Uo,
    unsigned short* __restrict__ Bp) {
  int u    = blockIdx.x * 256 + threadIdx.x;
  int lane = u & 63;
  int g    = (u >> 6) & 3;
  int wc   = (u >> 8) & 1;
  int kt   = (u >> 9) & 31;
  int bn   = u >> 14;
  int h    = bn * 32 + wc * 16 + (lane & 15);
  int k    = kt * 32 + ((lane >> 4) << 3);
  const float* src;
  if (k < 512) {
    const float* W = (g == 0) ? Wi : (g == 1) ? Wf : (g == 2) ? Wc : Wo;
    src = W + (uint64_t)h * 512 + k;
  } else {
    const float* U = (g == 0) ? Ui : (g == 1) ? Uf : (g == 2) ? Uc : Uo;
    src = U + (uint64_t)h * 512 + (k - 512);
  }
  floatx4 v0 = *reinterpret_cast<const floatx4*>(src);
  floatx4 v1 = *reinterpret_cast<const floatx4*>(src + 4);
  *reinterpret_cast<short8*>(Bp + (uint64_t)u * 8) = cvt8(v0, v1);
}

// ---- register-direct GEMM pieces ----
// load one tile's fragments straight from packed global (coalesced: each
// lane reads base + lane*16B). A: 8 frags (mh*2048 + m4*512), B: 4 frags.
#define LOADSET(AS, BS, PA, PB)                                             \
  _Pragma("unroll")                                                         \
  for (int m = 0; m < 8; ++m)                                               \
    AS[m] = *reinterpret_cast<const short8*>(                               \
        (PA) + ((m >> 2) * 2048 + (m & 3) * 512) + lane * 8);               \
  _Pragma("unroll")                                                         \
  for (int g = 0; g < 4; ++g)                                               \
    BS[g] = *reinterpret_cast<const short8*>((PB) + g * 512 + lane * 8);

#define COMPUTE(AS, BS)                                                     \
  __builtin_amdgcn_s_setprio(1);                                            \
  _Pragma("unroll")                                                         \
  for (int m = 0; m < 8; ++m)                                               \
    _Pragma("unroll")                                                       \
    for (int g = 0; g < 4; ++g)                                             \
      acc[m][g] = __builtin_amdgcn_mfma_f32_16x16x32_bf16(                  \
          AS[m], BS[g], acc[m][g], 0, 0, 0);                                \
  __builtin_amdgcn_s_setprio(0);

// ---------------------------------------------------------------------------
// GEMM M=16384 Np=2048 K=1024. Tile 256x128, 4 waves (2wr x 2wc), wave =
// 128 rows x 64 np, acc[8][4] = 128 regs. NO LDS, NO barriers: packed
// layouts are frag-linear, so each wave loads its MFMA fragments DIRECTLY
// from global into registers (1KB/instr coalesced), double-buffered reg
// sets, unroll-2 (static indexing). Every wave is an independent pipeline
// (AITER flatmm pattern); compiler inserts counted vmcnt from C deps.
// Per-CU unique bytes/tile-period ~48KB (L1 catches wr/wc pair sharing)
// -> under L2 budget -> MFMA-bound. Regs: 96 stage + 128 acc + misc < 256.
// ---------------------------------------------------------------------------
__global__ __launch_bounds__(256, 2) void lstm_gemm_kernel(
    const unsigned short* __restrict__ Ap,
    const unsigned short* __restrict__ Bp,
    const float* __restrict__ z,
    const float* __restrict__ b_i, const float* __restrict__ b_f,
    const float* __restrict__ b_c, const float* __restrict__ b_o,
    float* __restrict__ out) {
  int tid  = threadIdx.x;
  int bid  = blockIdx.x;
  int sw   = (bid & 7) * 128 + (bid >> 3);  // 1024 % 8 == 0 -> bijective
  int bn   = sw & 15;    // 16 N-tiles (32 h * 4 gates)
  int bm   = sw >> 4;    // 64 M-tiles (256 rows)
  int lane = tid & 63;
  int wid  = tid >> 6;   // 0..3
  int wr   = wid >> 1;   // 0..1 -> 128 rows
  int wc   = wid & 1;    // 0..1 -> 16 h * 4 gates

  floatx4 acc[8][4];
#pragma unroll
  for (int m = 0; m < 8; ++m)
#pragma unroll
    for (int g = 0; g < 4; ++g)
      acc[m][g] = (floatx4){0.f, 0.f, 0.f, 0.f};

  // wave-private panel bases (frag-linear packed global)
  const unsigned short* pA = Ap + (uint64_t)bm * (32 * 8192) + wr * 4096;
  const unsigned short* pB = Bp + (uint64_t)bn * (32 * 4096) + wc * 2048;

  short8 a0[8], b0[4], a1[8], b1[4];

  // prologue: sets for tiles 0 and 1
  LOADSET(a0, b0, pA, pB)
  LOADSET(a1, b1, pA + 8192, pB + 4096)

#pragma unroll 1
  for (int kt = 0; kt < 30; kt += 2) {
    const unsigned short* pA2 = pA + (kt + 2) * 8192;
    const unsigned short* pB2 = pB + (kt + 2) * 4096;
    COMPUTE(a0, b0)
    LOADSET(a0, b0, pA2, pB2)           // tile kt+2 into freed set0
    COMPUTE(a1, b1)
    LOADSET(a1, b1, pA2 + 8192, pB2 + 4096)  // tile kt+3 into freed set1
  }
  // tail: tiles 30, 31 already loaded
  COMPUTE(a0, b0)
  COMPUTE(a1, b1)

  // ---- fused LSTM epilogue (lane-local: acc frag index g == gate)
  int h = bn * 32 + wc * 16 + (lane & 15);
  float vbi = b_i[h], vbf = b_f[h], vbc = b_c[h], vbo = b_o[h];
  int rbase = bm * 256 + wr * 128 + ((lane >> 4) << 2);
  float* outH = out;
  float* outC = out + (uint64_t)B_DIM * H_DIM;
#pragma unroll
  for (int m = 0; m < 8; ++m) {
#pragma unroll
    for (int j = 0; j < 4; ++j) {
      int r = rbase + m * 16 + j;
      float pi = acc[m][0][j] + vbi;
      float pf = acc[m][1][j] + vbf;
      float pc = acc[m][2][j] + vbc;
      float po = acc[m][3][j] + vbo;
      float gi = 1.f / (1.f + __expf(-pi));
      float gf = 1.f / (1.f + __expf(-pf));
      float gc = 1.f - 2.f / (__expf(2.f * pc) + 1.f);  // tanh
      float go = 1.f / (1.f + __expf(-po));
      float zv = z[(uint64_t)r * H_DIM + h];
      float cn = gf * zv + gi * gc;
      float hn = go * (1.f - 2.f / (__expf(2.f * cn) + 1.f));
      outH[(uint64_t)r * H_DIM + h] = hn;
      outC[(uint64_t)r * H_DIM + h] = cn;
    }
  }
}

extern "C" void kernel_launch(void* const* d_in, const int* in_sizes, int n_in,
                              void* d_out, int out_size, void* d_ws, size_t ws_size,
                              hipStream_t stream) {
  const float* z  = (const float*)d_in[0];
  const float* x  = (const float*)d_in[1];
  const float* Wi = (const float*)d_in[2];
  const float* Wf = (const float*)d_in[3];
  const float* Wc = (const float*)d_in[4];
  const float* Wo = (const float*)d_in[5];
  const float* bi = (const float*)d_in[6];
  const float* bf = (const float*)d_in[7];
  const float* bc = (const float*)d_in[8];
  const float* bo = (const float*)d_in[9];
  const float* Ui = (const float*)d_in[10];
  const float* Uf = (const float*)d_in[11];
  const float* Uc = (const float*)d_in[12];
  const float* Uo = (const float*)d_in[13];

  unsigned short* Ap = (unsigned short*)d_ws;                          // 32 MB
  unsigned short* Bp = (unsigned short*)((char*)d_ws
                        + (size_t)B_DIM * KTOT * sizeof(unsigned short)); // +4 MB
  float* out = (float*)d_out;

  hipLaunchKernelGGL(pack_w_kernel, dim3((size_t)NP * KTOT / 8 / 256), dim3(256), 0, stream,
                     Wi, Wf, Wc, Wo, Ui, Uf, Uc, Uo, Bp);
  hipLaunchKernelGGL(pack_a_kernel, dim3((size_t)B_DIM * KTOT / 8 / 256), dim3(256), 0, stream,
                     x, z, Ap);
  hipLaunchKernelGGL(lstm_gemm_kernel, dim3(1024), dim3(256), 0, stream,
                     Ap, Bp, z, bi, bf, bc, bo, out);
}